// Round 7
// baseline (11.044 us; speedup 1.0000x reference)
//
#include <hip/hip_runtime.h>

#define BATCH 1024
#define FEAT_DIM 128
#define NUM_CLASSES 100000
#define NBLK 8
#define NTHREADS 1024

// Flattened fused center loss, ILP-4, minimal coherence tail.
// Work = 32768 float4 chunks of the (B,D) domain. 8 blocks x 1024 thr x 4.
// 32 consecutive lanes share a row, so the centers[labels[row]] gather is
// fully coalesced (one contiguous 512 B row per 32-lane group).
// Completion: one relaxed RMW per block; 8 consecutive increments cover
// every residue mod 8 exactly once -> old%8==7 identifies the last block
// of THIS call for ANY initial counter value (0xAA-poison-proof, no reset,
// monotone across graph replays). Last block acquire-fences and reduces
// the 8 partials in a fixed order -> out[0]. No float atomics; reduction
// order is fixed regardless of which block is last => deterministic.
__global__ __launch_bounds__(NTHREADS) void centerloss_fused(
    const float* __restrict__ x,
    const int* __restrict__ labels,
    const float* __restrict__ centers,
    float* partial,      // d_ws + 0    : 8 floats
    unsigned* cnt,       // d_ws + 4096 : 1 u32 (own cache line)
    float* out) {

    const int wave = threadIdx.x >> 6;                  // 0..15
    const int lane = threadIdx.x & 63;                  // 0..63

    const float4* x4 = reinterpret_cast<const float4*>(x);
    const float4* c4 = reinterpret_cast<const float4*>(centers);

    const int c0 = blockIdx.x * 4096 + threadIdx.x;     // ILP-4
    const int c1 = c0 + 1024;
    const int c2 = c0 + 2048;
    const int c3 = c0 + 3072;

    // labels (32-lane groups share a row -> coalesced/broadcast)
    const long long l0 = (long long)labels[c0 >> 5];
    const long long l1 = (long long)labels[c1 >> 5];
    const long long l2 = (long long)labels[c2 >> 5];
    const long long l3 = (long long)labels[c3 >> 5];

    // 8 independent 16B loads (4x x, 4x gathered-but-coalesced centers)
    const float4 xa = x4[c0], xb = x4[c1], xc = x4[c2], xd = x4[c3];
    const float4 ca = c4[l0 * 32 + (c0 & 31)];
    const float4 cb = c4[l1 * 32 + (c1 & 31)];
    const float4 cc = c4[l2 * 32 + (c2 & 31)];
    const float4 cd = c4[l3 * 32 + (c3 & 31)];

    float s;
    {
        const float a0 = xa.x - ca.x, a1 = xa.y - ca.y, a2 = xa.z - ca.z, a3 = xa.w - ca.w;
        const float b0 = xb.x - cb.x, b1 = xb.y - cb.y, b2 = xb.z - cb.z, b3 = xb.w - cb.w;
        const float g0 = xc.x - cc.x, g1 = xc.y - cc.y, g2 = xc.z - cc.z, g3 = xc.w - cc.w;
        const float h0 = xd.x - cd.x, h1 = xd.y - cd.y, h2 = xd.z - cd.z, h3 = xd.w - cd.w;
        s = (((a0 * a0 + a1 * a1) + (a2 * a2 + a3 * a3))
           + ((b0 * b0 + b1 * b1) + (b2 * b2 + b3 * b3)))
          + (((g0 * g0 + g1 * g1) + (g2 * g2 + g3 * g3))
           + ((h0 * h0 + h1 * h1) + (h2 * h2 + h3 * h3)));
    }

    // wave64 shuffle reduction (fixed order -> deterministic)
    #pragma unroll
    for (int o = 32; o > 0; o >>= 1)
        s += __shfl_down(s, o, 64);

    __shared__ float wsum[16];
    __shared__ unsigned old_s;
    if (lane == 0)
        wsum[wave] = s;
    __syncthreads();

    // wave 0 folds 16 wave-partials -> ONE block partial + counter bump
    if (threadIdx.x < 64) {
        float p = (lane < 16) ? wsum[lane] : 0.0f;
        #pragma unroll
        for (int o = 8; o > 0; o >>= 1)
            p += __shfl_down(p, o, 64);
        if (lane == 0) {
            __hip_atomic_store(&partial[blockIdx.x], p, __ATOMIC_RELAXED,
                               __HIP_MEMORY_SCOPE_AGENT);
            old_s = __hip_atomic_fetch_add(cnt, 1u, __ATOMIC_ACQ_REL,
                                           __HIP_MEMORY_SCOPE_AGENT);
        }
    }
    __syncthreads();

    if ((old_s & (NBLK - 1)) != (NBLK - 1)) return;     // not last block

    // ---- last block: fixed-order reduce of the 8 partials ----
    __builtin_amdgcn_fence(__ATOMIC_ACQUIRE, "agent");
    if (threadIdx.x < 64) {
        float p = (lane < NBLK)
                      ? __hip_atomic_load(&partial[lane], __ATOMIC_RELAXED,
                                          __HIP_MEMORY_SCOPE_AGENT)
                      : 0.0f;
        #pragma unroll
        for (int o = 4; o > 0; o >>= 1)
            p += __shfl_down(p, o, 64);
        if (lane == 0)
            out[0] = p * (1.0f / ((float)BATCH * (float)NUM_CLASSES));
    }
}

extern "C" void kernel_launch(void* const* d_in, const int* in_sizes, int n_in,
                              void* d_out, int out_size, void* d_ws, size_t ws_size,
                              hipStream_t stream) {
    const float* x       = (const float*)d_in[0];
    const int*   labels  = (const int*)d_in[1];
    const float* centers = (const float*)d_in[2];
    float*       out     = (float*)d_out;
    float*       partial = (float*)d_ws;                       // 32 B used
    unsigned*    cnt     = (unsigned*)((char*)d_ws + 4096);    // own line

    centerloss_fused<<<NBLK, NTHREADS, 0, stream>>>(x, labels, centers,
                                                    partial, cnt, out);
}

// Round 8
// 9.425 us; speedup vs baseline: 1.1719x; 1.1719x over previous
//
#include <hip/hip_runtime.h>

#define BATCH 1024
#define FEAT_DIM 128
#define NUM_CLASSES 100000
#define NBLK 16
#define NTHREADS 1024

// Flattened fused center loss (reverted to the round-6 best: 9.4 us).
// Work = 32768 float4 chunks of the (B,D) domain; 16 blocks x 1024 x ILP-2.
// 32 consecutive lanes share a row, so the centers[labels[row]] gather is
// fully coalesced (one contiguous 512 B row per 32-lane group).
// Completion: one relaxed RMW per block; 16 consecutive increments cover
// every residue mod 16 exactly once -> old%16==15 identifies the last
// block of THIS call for ANY initial counter value (0xAA-poison-proof,
// no reset, monotone across graph replays). Last block acquire-fences and
// reduces the 16 partials in a fixed order -> out[0]. No float atomics;
// reduction order fixed regardless of which block is last => deterministic.
//
// Perf decomposition (measured R1..R7): ~7 us graph-node launch floor +
// ~2 us dependent gather chain (labels -> scattered center row, both cold
// HBM) + ~0.4 us cross-XCD tail. 8 blocks (R7) regressed to 11.0 us:
// latency-bound => spread across more CUs, not more ILP per CU.
__global__ __launch_bounds__(NTHREADS) void centerloss_fused(
    const float* __restrict__ x,
    const int* __restrict__ labels,
    const float* __restrict__ centers,
    float* partial,      // d_ws + 0    : 16 floats
    unsigned* cnt,       // d_ws + 4096 : 1 u32 (own cache line)
    float* out) {

    const int wave = threadIdx.x >> 6;                  // 0..15
    const int lane = threadIdx.x & 63;                  // 0..63

    const float4* x4 = reinterpret_cast<const float4*>(x);
    const float4* c4 = reinterpret_cast<const float4*>(centers);

    const int chunk0 = blockIdx.x * 2048 + threadIdx.x; // ILP-2
    const int chunk1 = chunk0 + 1024;

    // row ids and labels (32-lane groups share a row -> broadcast)
    const int r0 = chunk0 >> 5, r1 = chunk1 >> 5;
    const long long l0 = (long long)labels[r0];
    const long long l1 = (long long)labels[r1];

    const float4 xa = x4[chunk0];
    const float4 xb = x4[chunk1];
    const float4 ca = c4[l0 * 32 + (chunk0 & 31)];      // coalesced gather
    const float4 cb = c4[l1 * 32 + (chunk1 & 31)];

    const float e0 = xa.x - ca.x, e1 = xa.y - ca.y;
    const float e2 = xa.z - ca.z, e3 = xa.w - ca.w;
    const float f0 = xb.x - cb.x, f1 = xb.y - cb.y;
    const float f2 = xb.z - cb.z, f3 = xb.w - cb.w;
    float s = ((e0 * e0 + e1 * e1) + (e2 * e2 + e3 * e3))
            + ((f0 * f0 + f1 * f1) + (f2 * f2 + f3 * f3));

    // wave64 shuffle reduction (fixed order -> deterministic)
    #pragma unroll
    for (int o = 32; o > 0; o >>= 1)
        s += __shfl_down(s, o, 64);

    __shared__ float wsum[16];
    __shared__ unsigned old_s;
    if (lane == 0)
        wsum[wave] = s;
    __syncthreads();

    // wave 0 folds 16 wave-partials -> ONE block partial + counter bump
    if (threadIdx.x < 64) {
        float p = (lane < 16) ? wsum[lane] : 0.0f;
        #pragma unroll
        for (int o = 8; o > 0; o >>= 1)
            p += __shfl_down(p, o, 64);
        if (lane == 0) {
            __hip_atomic_store(&partial[blockIdx.x], p, __ATOMIC_RELAXED,
                               __HIP_MEMORY_SCOPE_AGENT);
            old_s = __hip_atomic_fetch_add(cnt, 1u, __ATOMIC_ACQ_REL,
                                           __HIP_MEMORY_SCOPE_AGENT);
        }
    }
    __syncthreads();

    if ((old_s & (NBLK - 1)) != (NBLK - 1)) return;     // not last block

    // ---- last block: fixed-order reduce of the 16 partials ----
    __builtin_amdgcn_fence(__ATOMIC_ACQUIRE, "agent");
    if (threadIdx.x < 64) {
        float p = (lane < NBLK)
                      ? __hip_atomic_load(&partial[lane], __ATOMIC_RELAXED,
                                          __HIP_MEMORY_SCOPE_AGENT)
                      : 0.0f;
        #pragma unroll
        for (int o = 8; o > 0; o >>= 1)
            p += __shfl_down(p, o, 64);
        if (lane == 0)
            out[0] = p * (1.0f / ((float)BATCH * (float)NUM_CLASSES));
    }
}

extern "C" void kernel_launch(void* const* d_in, const int* in_sizes, int n_in,
                              void* d_out, int out_size, void* d_ws, size_t ws_size,
                              hipStream_t stream) {
    const float* x       = (const float*)d_in[0];
    const int*   labels  = (const int*)d_in[1];
    const float* centers = (const float*)d_in[2];
    float*       out     = (float*)d_out;
    float*       partial = (float*)d_ws;                       // 64 B used
    unsigned*    cnt     = (unsigned*)((char*)d_ws + 4096);    // own line

    centerloss_fused<<<NBLK, NTHREADS, 0, stream>>>(x, labels, centers,
                                                    partial, cnt, out);
}